// Round 1
// baseline (1035.182 us; speedup 1.0000x reference)
//
#include <hip/hip_runtime.h>

#define S_TOK 16384   // S*N tokens
#define D_DIM 1024
#define F_DIM 4096
#define E_NUM 8

#define BM 128
#define BN 128
#define BK 32
#define LSTR 40       // BK + 8 pad (bf16 elements)

typedef short bf16x8 __attribute__((ext_vector_type(8)));
typedef float f32x4 __attribute__((ext_vector_type(4)));

static __device__ __forceinline__ unsigned short f32_bf16(float f) {
  unsigned u = __float_as_uint(f);
  return (unsigned short)((u + 0x7FFFu + ((u >> 16) & 1u)) >> 16);
}

static __device__ __forceinline__ unsigned int pack_bf16x2(float a, float b) {
  unsigned ua = __float_as_uint(a);
  unsigned ub = __float_as_uint(b);
  unsigned lo = (ua + 0x7FFFu + ((ua >> 16) & 1u)) >> 16;
  unsigned hi = (ub + 0x7FFFu + ((ub >> 16) & 1u)) & 0xFFFF0000u;
  return lo | hi;
}

static __device__ __forceinline__ uint2 cvt_f4_bf4(const float4 v) {
  uint2 r;
  r.x = pack_bf16x2(v.x, v.y);
  r.y = pack_bf16x2(v.z, v.w);
  return r;
}

// ---------------- zero counts ----------------
__global__ void zero_counts_kernel(int* counts) {
  if (threadIdx.x < E_NUM) counts[threadIdx.x] = 0;
}

// ---------------- gating ----------------
// one wave per token: scores = x . Wg^T (fp32), softmax, argmax(first), bucket.
__global__ void gate_kernel(const float* __restrict__ x,
                            const float* __restrict__ Wg,
                            float* __restrict__ prob,
                            int* __restrict__ counts,
                            int* __restrict__ tok_list) {
  const int wave = threadIdx.x >> 6;
  const int lane = threadIdx.x & 63;
  const int t = blockIdx.x * 4 + wave;
  const float* xr = x + (size_t)t * D_DIM;

  float acc[E_NUM];
#pragma unroll
  for (int e = 0; e < E_NUM; ++e) acc[e] = 0.0f;

  for (int k = lane; k < D_DIM; k += 64) {
    float xv = xr[k];
#pragma unroll
    for (int e = 0; e < E_NUM; ++e) acc[e] += xv * Wg[e * D_DIM + k];
  }
#pragma unroll
  for (int e = 0; e < E_NUM; ++e) {
#pragma unroll
    for (int off = 32; off > 0; off >>= 1)
      acc[e] += __shfl_xor(acc[e], off, 64);
  }
  if (lane == 0) {
    float m = acc[0]; int bi = 0;
#pragma unroll
    for (int e = 1; e < E_NUM; ++e) {
      if (acc[e] > m) { m = acc[e]; bi = e; }
    }
    float s = 0.0f;
#pragma unroll
    for (int e = 0; e < E_NUM; ++e) s += expf(acc[e] - m);
    prob[t] = 1.0f / s;             // softmax prob of the max logit
    int p = atomicAdd(&counts[bi], 1);
    tok_list[bi * S_TOK + p] = t;
  }
}

// ---------------- FFN layer 1: H = gelu(x @ W1[e]^T + b1[e]) ----------------
// grouped GEMM, A = gathered token rows (fp32 -> bf16), B = W1[e] rows (fp32 -> bf16)
__launch_bounds__(256, 2)
__global__ void ffn1_kernel(const float* __restrict__ x,
                            const float* __restrict__ W1,
                            const float* __restrict__ b1,
                            const int* __restrict__ counts,
                            const int* __restrict__ tok_list,
                            unsigned short* __restrict__ H) {
  const int e = blockIdx.z;
  const int cnt = counts[e];
  const int m0 = blockIdx.y * BM;
  if (m0 >= cnt) return;
  const int n0 = blockIdx.x * BN;

  __shared__ unsigned short As[BM * LSTR];
  __shared__ unsigned short Bs[BN * LSTR];

  const int tid = threadIdx.x;
  const int lane = tid & 63;
  const int wv = tid >> 6;
  const int wr = (wv >> 1) * 64;
  const int wc = (wv & 1) * 64;

  // staging: 2 threads per row, 16 floats each
  const int srow = tid >> 1;
  const int shalf = (tid & 1) * 16;

  const int arow_valid = (m0 + srow) < cnt;
  const int tokA = arow_valid ? tok_list[e * S_TOK + m0 + srow] : 0;
  const float* aptr = x + (size_t)tokA * D_DIM + shalf;
  const float* bptr = W1 + (size_t)e * F_DIM * D_DIM + (size_t)(n0 + srow) * D_DIM + shalf;

  f32x4 acc[4][4];
#pragma unroll
  for (int i = 0; i < 4; ++i)
#pragma unroll
    for (int j = 0; j < 4; ++j)
      acc[i][j] = (f32x4){0.f, 0.f, 0.f, 0.f};

  for (int k0 = 0; k0 < D_DIM; k0 += BK) {
    // stage A
    {
      uint4 w0, w1;
      if (arow_valid) {
        const float4* p = (const float4*)(aptr + k0);
        float4 v0 = p[0], v1 = p[1], v2 = p[2], v3 = p[3];
        uint2 a0 = cvt_f4_bf4(v0), a1 = cvt_f4_bf4(v1);
        uint2 a2 = cvt_f4_bf4(v2), a3 = cvt_f4_bf4(v3);
        w0.x = a0.x; w0.y = a0.y; w0.z = a1.x; w0.w = a1.y;
        w1.x = a2.x; w1.y = a2.y; w1.z = a3.x; w1.w = a3.y;
      } else {
        w0.x = w0.y = w0.z = w0.w = 0u;
        w1.x = w1.y = w1.z = w1.w = 0u;
      }
      uint4* dst = (uint4*)&As[srow * LSTR + shalf];
      dst[0] = w0; dst[1] = w1;
    }
    // stage B (rows always valid: F_DIM % BN == 0)
    {
      const float4* p = (const float4*)(bptr + k0);
      float4 v0 = p[0], v1 = p[1], v2 = p[2], v3 = p[3];
      uint2 a0 = cvt_f4_bf4(v0), a1 = cvt_f4_bf4(v1);
      uint2 a2 = cvt_f4_bf4(v2), a3 = cvt_f4_bf4(v3);
      uint4 w0, w1;
      w0.x = a0.x; w0.y = a0.y; w0.z = a1.x; w0.w = a1.y;
      w1.x = a2.x; w1.y = a2.y; w1.z = a3.x; w1.w = a3.y;
      uint4* dst = (uint4*)&Bs[srow * LSTR + shalf];
      dst[0] = w0; dst[1] = w1;
    }
    __syncthreads();

    {
      const unsigned short* Ab = As + (wr + (lane & 15)) * LSTR + ((lane >> 4) * 8);
      const unsigned short* Bb = Bs + (wc + (lane & 15)) * LSTR + ((lane >> 4) * 8);
      bf16x8 a[4], b[4];
#pragma unroll
      for (int i = 0; i < 4; ++i) {
        a[i] = *(const bf16x8*)(Ab + i * 16 * LSTR);
        b[i] = *(const bf16x8*)(Bb + i * 16 * LSTR);
      }
#pragma unroll
      for (int mi = 0; mi < 4; ++mi)
#pragma unroll
        for (int ni = 0; ni < 4; ++ni)
          acc[mi][ni] = __builtin_amdgcn_mfma_f32_16x16x32_bf16(a[mi], b[ni], acc[mi][ni], 0, 0, 0);
    }
    __syncthreads();
  }

  // epilogue: bias + exact gelu, store bf16 H[tok][f]
  const float* b1e = b1 + (size_t)e * F_DIM;
#pragma unroll
  for (int mi = 0; mi < 4; ++mi) {
#pragma unroll
    for (int r = 0; r < 4; ++r) {
      const int slot = m0 + wr + mi * 16 + ((lane >> 4) * 4) + r;
      if (slot >= cnt) continue;
      const int tok = tok_list[e * S_TOK + slot];
      unsigned short* hrow = H + (size_t)tok * F_DIM;
#pragma unroll
      for (int ni = 0; ni < 4; ++ni) {
        const int col = n0 + wc + ni * 16 + (lane & 15);
        float v = acc[mi][ni][r] + b1e[col];
        v = 0.5f * v * (1.0f + erff(v * 0.70710678118654752f));
        hrow[col] = f32_bf16(v);
      }
    }
  }
}

// ---------------- FFN layer 2: y = prob * (H @ W2[e]^T + b2[e]) ----------------
__launch_bounds__(256, 2)
__global__ void ffn2_kernel(const unsigned short* __restrict__ H,
                            const float* __restrict__ W2,
                            const float* __restrict__ b2,
                            const float* __restrict__ prob,
                            const int* __restrict__ counts,
                            const int* __restrict__ tok_list,
                            float* __restrict__ out) {
  const int e = blockIdx.z;
  const int cnt = counts[e];
  const int m0 = blockIdx.y * BM;
  if (m0 >= cnt) return;
  const int n0 = blockIdx.x * BN;

  __shared__ unsigned short As[BM * LSTR];
  __shared__ unsigned short Bs[BN * LSTR];

  const int tid = threadIdx.x;
  const int lane = tid & 63;
  const int wv = tid >> 6;
  const int wr = (wv >> 1) * 64;
  const int wc = (wv & 1) * 64;

  const int srow = tid >> 1;
  const int shalf = (tid & 1) * 16;

  const int arow_valid = (m0 + srow) < cnt;
  const int tokA = arow_valid ? tok_list[e * S_TOK + m0 + srow] : 0;
  const unsigned short* aptr = H + (size_t)tokA * F_DIM + shalf;
  const float* bptr = W2 + (size_t)e * D_DIM * F_DIM + (size_t)(n0 + srow) * F_DIM + shalf;

  f32x4 acc[4][4];
#pragma unroll
  for (int i = 0; i < 4; ++i)
#pragma unroll
    for (int j = 0; j < 4; ++j)
      acc[i][j] = (f32x4){0.f, 0.f, 0.f, 0.f};

  for (int k0 = 0; k0 < F_DIM; k0 += BK) {
    // stage A (already bf16: direct copy)
    {
      uint4 w0, w1;
      if (arow_valid) {
        const uint4* p = (const uint4*)(aptr + k0);
        w0 = p[0]; w1 = p[1];
      } else {
        w0.x = w0.y = w0.z = w0.w = 0u;
        w1.x = w1.y = w1.z = w1.w = 0u;
      }
      uint4* dst = (uint4*)&As[srow * LSTR + shalf];
      dst[0] = w0; dst[1] = w1;
    }
    // stage B (fp32 -> bf16)
    {
      const float4* p = (const float4*)(bptr + k0);
      float4 v0 = p[0], v1 = p[1], v2 = p[2], v3 = p[3];
      uint2 a0 = cvt_f4_bf4(v0), a1 = cvt_f4_bf4(v1);
      uint2 a2 = cvt_f4_bf4(v2), a3 = cvt_f4_bf4(v3);
      uint4 w0, w1;
      w0.x = a0.x; w0.y = a0.y; w0.z = a1.x; w0.w = a1.y;
      w1.x = a2.x; w1.y = a2.y; w1.z = a3.x; w1.w = a3.y;
      uint4* dst = (uint4*)&Bs[srow * LSTR + shalf];
      dst[0] = w0; dst[1] = w1;
    }
    __syncthreads();

    {
      const unsigned short* Ab = As + (wr + (lane & 15)) * LSTR + ((lane >> 4) * 8);
      const unsigned short* Bb = Bs + (wc + (lane & 15)) * LSTR + ((lane >> 4) * 8);
      bf16x8 a[4], b[4];
#pragma unroll
      for (int i = 0; i < 4; ++i) {
        a[i] = *(const bf16x8*)(Ab + i * 16 * LSTR);
        b[i] = *(const bf16x8*)(Bb + i * 16 * LSTR);
      }
#pragma unroll
      for (int mi = 0; mi < 4; ++mi)
#pragma unroll
        for (int ni = 0; ni < 4; ++ni)
          acc[mi][ni] = __builtin_amdgcn_mfma_f32_16x16x32_bf16(a[mi], b[ni], acc[mi][ni], 0, 0, 0);
    }
    __syncthreads();
  }

  const float* b2e = b2 + (size_t)e * D_DIM;
#pragma unroll
  for (int mi = 0; mi < 4; ++mi) {
#pragma unroll
    for (int r = 0; r < 4; ++r) {
      const int slot = m0 + wr + mi * 16 + ((lane >> 4) * 4) + r;
      if (slot >= cnt) continue;
      const int tok = tok_list[e * S_TOK + slot];
      const float p = prob[tok];
      float* orow = out + (size_t)tok * D_DIM;
#pragma unroll
      for (int ni = 0; ni < 4; ++ni) {
        const int col = n0 + wc + ni * 16 + (lane & 15);
        orow[col] = (acc[mi][ni][r] + b2e[col]) * p;
      }
    }
  }
}

extern "C" void kernel_launch(void* const* d_in, const int* in_sizes, int n_in,
                              void* d_out, int out_size, void* d_ws, size_t ws_size,
                              hipStream_t stream) {
  const float* x  = (const float*)d_in[0];
  const float* Wg = (const float*)d_in[1];
  const float* W1 = (const float*)d_in[2];
  const float* b1 = (const float*)d_in[3];
  const float* W2 = (const float*)d_in[4];
  const float* b2 = (const float*)d_in[5];
  float* out = (float*)d_out;

  // ws layout: counts (256 B) | prob (64 KB) | tok_list (512 KB) | H bf16 (128 MB @ 1 MB)
  char* ws = (char*)d_ws;
  int* counts = (int*)ws;
  float* prob = (float*)(ws + 256);
  int* tok_list = (int*)(ws + 256 + 65536);
  unsigned short* H = (unsigned short*)(ws + (1u << 20));

  zero_counts_kernel<<<1, 64, 0, stream>>>(counts);
  gate_kernel<<<S_TOK / 4, 256, 0, stream>>>(x, Wg, prob, counts, tok_list);

  dim3 g1(F_DIM / BN, S_TOK / BM, E_NUM);   // 32 x 128 x 8 (early-exit past counts)
  ffn1_kernel<<<g1, 256, 0, stream>>>(x, W1, b1, counts, tok_list, H);

  dim3 g2(D_DIM / BN, S_TOK / BM, E_NUM);   // 8 x 128 x 8
  ffn2_kernel<<<g2, 256, 0, stream>>>(H, W2, b2, prob, counts, tok_list, out);
}

// Round 2
// 791.882 us; speedup vs baseline: 1.3072x; 1.3072x over previous
//
#include <hip/hip_runtime.h>

#define S_TOK 16384   // S*N tokens
#define D_DIM 1024
#define F_DIM 4096
#define E_NUM 8

#define BM 128
#define BN 128
#define BK 32

typedef short bf16x8 __attribute__((ext_vector_type(8)));
typedef float f32x4 __attribute__((ext_vector_type(4)));
typedef unsigned short ushort_t;

static __device__ __forceinline__ unsigned short f32_bf16(float f) {
  unsigned u = __float_as_uint(f);
  return (unsigned short)((u + 0x7FFFu + ((u >> 16) & 1u)) >> 16);
}

static __device__ __forceinline__ unsigned int pack_bf16x2(float a, float b) {
  unsigned ua = __float_as_uint(a);
  unsigned ub = __float_as_uint(b);
  unsigned lo = (ua + 0x7FFFu + ((ua >> 16) & 1u)) >> 16;
  unsigned hi = (ub + 0x7FFFu + ((ub >> 16) & 1u)) & 0xFFFF0000u;
  return lo | hi;
}

static __device__ __forceinline__ uint2 cvt_f4_bf4(const float4 v) {
  uint2 r;
  r.x = pack_bf16x2(v.x, v.y);
  r.y = pack_bf16x2(v.z, v.w);
  return r;
}

static __device__ __forceinline__ void load_lds16(const void* g, void* l) {
  __builtin_amdgcn_global_load_lds(g, l, 16, 0, 0);
}

// ---------------- zero counts ----------------
__global__ void zero_counts_kernel(int* counts) {
  if (threadIdx.x < E_NUM) counts[threadIdx.x] = 0;
}

// ---------------- fp32 -> bf16 cast (weights) ----------------
// each thread: 8 floats -> 8 bf16 (32B read, 16B write)
__global__ void cast_kernel(const float* __restrict__ in, ushort_t* __restrict__ out) {
  const size_t base = ((size_t)blockIdx.x * blockDim.x + threadIdx.x) * 8;
  const float4 v0 = *(const float4*)(in + base);
  const float4 v1 = *(const float4*)(in + base + 4);
  const uint2 a = cvt_f4_bf4(v0), b = cvt_f4_bf4(v1);
  uint4 w; w.x = a.x; w.y = a.y; w.z = b.x; w.w = b.y;
  *(uint4*)(out + base) = w;
}

// ---------------- gating (+ x cast to bf16) ----------------
// one wave per token: scores = x . Wg^T (fp32), softmax, argmax(first), bucket.
__global__ void gate_kernel(const float* __restrict__ x,
                            const float* __restrict__ Wg,
                            ushort_t* __restrict__ xbf,
                            float* __restrict__ prob,
                            int* __restrict__ counts,
                            int* __restrict__ tok_list) {
  const int wv = threadIdx.x >> 6;
  const int lane = threadIdx.x & 63;
  const int t = blockIdx.x * 4 + wv;
  const float* xr = x + (size_t)t * D_DIM;
  ushort_t* xb = xbf + (size_t)t * D_DIM;

  float acc[E_NUM];
#pragma unroll
  for (int e = 0; e < E_NUM; ++e) acc[e] = 0.0f;

#pragma unroll
  for (int i = 0; i < 4; ++i) {
    const int k = i * 256 + lane * 4;
    const float4 v = *(const float4*)(xr + k);
    *(uint2*)(xb + k) = cvt_f4_bf4(v);
#pragma unroll
    for (int e = 0; e < E_NUM; ++e) {
      const float4 w = *(const float4*)(Wg + e * D_DIM + k);
      acc[e] += v.x * w.x + v.y * w.y + v.z * w.z + v.w * w.w;
    }
  }
#pragma unroll
  for (int e = 0; e < E_NUM; ++e) {
#pragma unroll
    for (int off = 32; off > 0; off >>= 1)
      acc[e] += __shfl_xor(acc[e], off, 64);
  }
  if (lane == 0) {
    float m = acc[0]; int bi = 0;
#pragma unroll
    for (int e = 1; e < E_NUM; ++e) {
      if (acc[e] > m) { m = acc[e]; bi = e; }
    }
    float s = 0.0f;
#pragma unroll
    for (int e = 0; e < E_NUM; ++e) s += expf(acc[e] - m);
    prob[t] = 1.0f / s;             // softmax prob of the argmax logit
    int p = atomicAdd(&counts[bi], 1);
    tok_list[bi * S_TOK + p] = t;
  }
}

// ---------------- grouped GEMM (m97 structure) ----------------
// C[m][n] = sum_k A[tok[m]][k] * B[e][n][k]   (both row-major, K contiguous)
// EPI=0: H[tok][n] = bf16(gelu(C + b[n]))     (NDIM = F)
// EPI=1: out[tok][n] = (C + b[n]) * prob[tok] (NDIM = D)
template <int KDIM, int NDIM, int EPI>
__global__ void ffn_kernel(const ushort_t* __restrict__ A,
                           const ushort_t* __restrict__ B,
                           const float* __restrict__ bias,
                           const float* __restrict__ prob,
                           const int* __restrict__ counts,
                           const int* __restrict__ tok_list,
                           ushort_t* __restrict__ Hout,
                           float* __restrict__ out) {
  const int e = blockIdx.z;
  const int cnt = counts[e];
  const int m0 = blockIdx.y * BM;
  if (m0 >= cnt) return;
  const int n0 = blockIdx.x * BN;

  __shared__ ushort_t As[BM * BK];   // 8 KB, linear row-major [128][32]
  __shared__ ushort_t Bs[BN * BK];   // 8 KB

  const int tid = threadIdx.x;
  const int lane = tid & 63;
  const int w = tid >> 6;
  const int wr = (w >> 1) * 64;
  const int wc = (w & 1) * 64;

  // staging geometry: instr covers 64 rows; lane l -> row +(l>>2), elem (l&3)*8
  const int r0 = tid >> 2;          // rows 0..63
  const int r1 = 64 + r0;           // rows 64..127
  const int cb = (tid & 3) * 8;     // element offset within row

  const size_t ebase = (size_t)e * S_TOK;
  const int tokA0 = (m0 + r0 < cnt) ? tok_list[ebase + m0 + r0] : 0;
  const int tokA1 = (m0 + r1 < cnt) ? tok_list[ebase + m0 + r1] : 0;
  const ushort_t* pA0 = A + (size_t)tokA0 * KDIM + cb;
  const ushort_t* pA1 = A + (size_t)tokA1 * KDIM + cb;
  const ushort_t* Be = B + (size_t)e * NDIM * KDIM;
  const ushort_t* pB0 = Be + (size_t)(n0 + r0) * KDIM + cb;
  const ushort_t* pB1 = Be + (size_t)(n0 + r1) * KDIM + cb;

  // wave-uniform LDS bases (elements): instr0 -> rows 16w.., instr1 -> rows 64+16w..
  ushort_t* lA0 = &As[w * 512];
  ushort_t* lA1 = &As[2048 + w * 512];
  ushort_t* lB0 = &Bs[w * 512];
  ushort_t* lB1 = &Bs[2048 + w * 512];

  f32x4 acc[4][4];
#pragma unroll
  for (int i = 0; i < 4; ++i)
#pragma unroll
    for (int j = 0; j < 4; ++j)
      acc[i][j] = (f32x4){0.f, 0.f, 0.f, 0.f};

  for (int k0 = 0; k0 < KDIM; k0 += BK) {
    load_lds16(pA0 + k0, lA0);
    load_lds16(pA1 + k0, lA1);
    load_lds16(pB0 + k0, lB0);
    load_lds16(pB1 + k0, lB1);
    __syncthreads();

    const ushort_t* Ab = &As[(wr + (lane & 15)) * BK + (lane >> 4) * 8];
    const ushort_t* Bb = &Bs[(wc + (lane & 15)) * BK + (lane >> 4) * 8];
    bf16x8 a[4], b[4];
#pragma unroll
    for (int i = 0; i < 4; ++i) {
      a[i] = *(const bf16x8*)(Ab + i * 16 * BK);
      b[i] = *(const bf16x8*)(Bb + i * 16 * BK);
    }
#pragma unroll
    for (int mi = 0; mi < 4; ++mi)
#pragma unroll
      for (int ni = 0; ni < 4; ++ni)
        acc[mi][ni] = __builtin_amdgcn_mfma_f32_16x16x32_bf16(a[mi], b[ni], acc[mi][ni], 0, 0, 0);
    __syncthreads();
  }

  const float* be = bias + (size_t)e * NDIM;
#pragma unroll
  for (int mi = 0; mi < 4; ++mi) {
#pragma unroll
    for (int r = 0; r < 4; ++r) {
      const int slot = m0 + wr + mi * 16 + ((lane >> 4) * 4) + r;
      if (slot >= cnt) continue;
      const int tok = tok_list[ebase + slot];
      if (EPI == 0) {
        ushort_t* hrow = Hout + (size_t)tok * NDIM;
#pragma unroll
        for (int ni = 0; ni < 4; ++ni) {
          const int col = n0 + wc + ni * 16 + (lane & 15);
          float v = acc[mi][ni][r] + be[col];
          v = 0.5f * v * (1.0f + erff(v * 0.70710678118654752f));
          hrow[col] = f32_bf16(v);
        }
      } else {
        const float p = prob[tok];
        float* orow = out + (size_t)tok * NDIM;
#pragma unroll
        for (int ni = 0; ni < 4; ++ni) {
          const int col = n0 + wc + ni * 16 + (lane & 15);
          orow[col] = (acc[mi][ni][r] + be[col]) * p;
        }
      }
    }
  }
}

extern "C" void kernel_launch(void* const* d_in, const int* in_sizes, int n_in,
                              void* d_out, int out_size, void* d_ws, size_t ws_size,
                              hipStream_t stream) {
  const float* x  = (const float*)d_in[0];
  const float* Wg = (const float*)d_in[1];
  const float* W1 = (const float*)d_in[2];
  const float* b1 = (const float*)d_in[3];
  const float* W2 = (const float*)d_in[4];
  const float* b2 = (const float*)d_in[5];
  float* out = (float*)d_out;

  const size_t MB = 1ull << 20;
  char* ws = (char*)d_ws;
  int* counts      = (int*)(ws);                 // 32 B
  float* prob      = (float*)(ws + 64 * 1024);   // 64 KB
  int* tok_list    = (int*)(ws + 128 * 1024);    // 512 KB
  ushort_t* xbf    = (ushort_t*)(ws + 1 * MB);   // 32 MB
  ushort_t* W1bf   = (ushort_t*)(ws + 33 * MB);  // 64 MB
  ushort_t* W2bf   = (ushort_t*)(ws + 97 * MB);  // 64 MB
  ushort_t* H      = (ushort_t*)(ws + 161 * MB); // 128 MB

  zero_counts_kernel<<<1, 64, 0, stream>>>(counts);
  gate_kernel<<<S_TOK / 4, 256, 0, stream>>>(x, Wg, xbf, prob, counts, tok_list);

  // cast W1, W2 (each 8*4096*1024 = 33554432 floats; /8 per thread /256 per block)
  cast_kernel<<<16384, 256, 0, stream>>>(W1, W1bf);
  cast_kernel<<<16384, 256, 0, stream>>>(W2, W2bf);

  dim3 g1(F_DIM / BN, S_TOK / BM, E_NUM);   // 32 x 128 x 8 (early-exit past counts)
  ffn_kernel<D_DIM, F_DIM, 0><<<g1, 256, 0, stream>>>(xbf, W1bf, b1, nullptr, counts, tok_list, H, nullptr);

  dim3 g2(D_DIM / BN, S_TOK / BM, E_NUM);   // 8 x 128 x 8
  ffn_kernel<F_DIM, D_DIM, 1><<<g2, 256, 0, stream>>>(H, W2bf, b2, prob, counts, tok_list, nullptr, out);
}

// Round 3
// 780.479 us; speedup vs baseline: 1.3263x; 1.0146x over previous
//
#include <hip/hip_runtime.h>

#define S_TOK 16384   // S*N tokens
#define D_DIM 1024
#define F_DIM 4096
#define E_NUM 8

#define BM 128
#define BN 128
#define BK 32
#define NTILES_MAX 136   // sum_e ceil(cnt_e/BM) <= S_TOK/BM + E_NUM = 136

typedef short bf16x8 __attribute__((ext_vector_type(8)));
typedef float f32x4 __attribute__((ext_vector_type(4)));
typedef unsigned short ushort_t;

static __device__ __forceinline__ unsigned short f32_bf16(float f) {
  unsigned u = __float_as_uint(f);
  return (unsigned short)((u + 0x7FFFu + ((u >> 16) & 1u)) >> 16);
}

static __device__ __forceinline__ unsigned int pack_bf16x2(float a, float b) {
  unsigned ua = __float_as_uint(a);
  unsigned ub = __float_as_uint(b);
  unsigned lo = (ua + 0x7FFFu + ((ua >> 16) & 1u)) >> 16;
  unsigned hi = (ub + 0x7FFFu + ((ub >> 16) & 1u)) & 0xFFFF0000u;
  return lo | hi;
}

static __device__ __forceinline__ uint2 cvt_f4_bf4(const float4 v) {
  uint2 r;
  r.x = pack_bf16x2(v.x, v.y);
  r.y = pack_bf16x2(v.z, v.w);
  return r;
}

static __device__ __forceinline__ void load_lds16(const void* g, void* l) {
  __builtin_amdgcn_global_load_lds(g, l, 16, 0, 0);
}

// ---------------- zero counts ----------------
__global__ void zero_counts_kernel(int* counts) {
  if (threadIdx.x < E_NUM) counts[threadIdx.x] = 0;
}

// ---------------- fp32 -> bf16 cast (weights) ----------------
__global__ void cast_kernel(const float* __restrict__ in, ushort_t* __restrict__ out) {
  const size_t base = ((size_t)blockIdx.x * blockDim.x + threadIdx.x) * 8;
  const float4 v0 = *(const float4*)(in + base);
  const float4 v1 = *(const float4*)(in + base + 4);
  const uint2 a = cvt_f4_bf4(v0), b = cvt_f4_bf4(v1);
  uint4 w; w.x = a.x; w.y = a.y; w.z = b.x; w.w = b.y;
  *(uint4*)(out + base) = w;
}

// ---------------- gating (+ x cast to bf16) ----------------
__global__ void gate_kernel(const float* __restrict__ x,
                            const float* __restrict__ Wg,
                            ushort_t* __restrict__ xbf,
                            float* __restrict__ prob,
                            int* __restrict__ counts,
                            int* __restrict__ tok_list) {
  const int wv = threadIdx.x >> 6;
  const int lane = threadIdx.x & 63;
  const int t = blockIdx.x * 4 + wv;
  const float* xr = x + (size_t)t * D_DIM;
  ushort_t* xb = xbf + (size_t)t * D_DIM;

  float acc[E_NUM];
#pragma unroll
  for (int e = 0; e < E_NUM; ++e) acc[e] = 0.0f;

#pragma unroll
  for (int i = 0; i < 4; ++i) {
    const int k = i * 256 + lane * 4;
    const float4 v = *(const float4*)(xr + k);
    *(uint2*)(xb + k) = cvt_f4_bf4(v);
#pragma unroll
    for (int e = 0; e < E_NUM; ++e) {
      const float4 w = *(const float4*)(Wg + e * D_DIM + k);
      acc[e] += v.x * w.x + v.y * w.y + v.z * w.z + v.w * w.w;
    }
  }
#pragma unroll
  for (int e = 0; e < E_NUM; ++e) {
#pragma unroll
    for (int off = 32; off > 0; off >>= 1)
      acc[e] += __shfl_xor(acc[e], off, 64);
  }
  if (lane == 0) {
    float m = acc[0]; int bi = 0;
#pragma unroll
    for (int e = 1; e < E_NUM; ++e) {
      if (acc[e] > m) { m = acc[e]; bi = e; }
    }
    float s = 0.0f;
#pragma unroll
    for (int e = 0; e < E_NUM; ++e) s += expf(acc[e] - m);
    prob[t] = 1.0f / s;             // softmax prob of the argmax logit
    int p = atomicAdd(&counts[bi], 1);
    tok_list[bi * S_TOK + p] = t;
  }
}

// ---------------- tile plan: dense (expert, m0) table ----------------
// plan[0] = ntiles; plan[1+i] = expert of tile i; plan[1+NTILES_MAX+i] = m0
__global__ void plan_kernel(const int* __restrict__ counts, int* __restrict__ plan) {
  if (threadIdx.x == 0) {
    int t = 0;
    for (int e = 0; e < E_NUM; ++e) {
      const int nt = (counts[e] + BM - 1) / BM;
      for (int i = 0; i < nt; ++i) {
        plan[1 + t] = e;
        plan[1 + NTILES_MAX + t] = i * BM;
        ++t;
      }
    }
    plan[0] = t;
  }
}

// ---------------- grouped GEMM (dense grid, double-buffered LDS) ----------------
// C[m][n] = sum_k A[tok[m]][k] * B[e][n][k]
// EPI=0: H[tok][n] = bf16(gelu(C + b[n]))     (NDIM = F)
// EPI=1: out[tok][n] = (C + b[n]) * prob[tok] (NDIM = D)
template <int KDIM, int NDIM, int EPI>
__launch_bounds__(256, 4)
__global__ void ffn_kernel(const ushort_t* __restrict__ A,
                           const ushort_t* __restrict__ B,
                           const float* __restrict__ bias,
                           const float* __restrict__ prob,
                           const int* __restrict__ counts,
                           const int* __restrict__ tok_list,
                           const int* __restrict__ plan,
                           ushort_t* __restrict__ Hout,
                           float* __restrict__ out) {
  constexpr int NT = NDIM / BN;
  constexpr int NWG = NT * NTILES_MAX;   // divisible by 8 for NT=8/32
  const int ntiles = plan[0];
  // bijective XCD-chunk swizzle: XCD k owns wg range [k*NWG/8, (k+1)*NWG/8)
  const int wg = (blockIdx.x & 7) * (NWG >> 3) + (blockIdx.x >> 3);
  const int tile = wg / NT;            // m-tile slow, n fast: A-panel hot per XCD
  if (tile >= ntiles) return;
  const int n0 = (wg % NT) * BN;
  const int e = plan[1 + tile];
  const int m0 = plan[1 + NTILES_MAX + tile];
  const int cnt = counts[e];

  __shared__ ushort_t As[2][BM * BK];   // 2 x 8 KB
  __shared__ ushort_t Bs[2][BM * BK];   // 2 x 8 KB

  const int tid = threadIdx.x;
  const int lane = tid & 63;
  const int w = tid >> 6;
  const int wr = (w >> 1) * 64;
  const int wc = (w & 1) * 64;

  // staging geometry: each global_load_lds covers 64 rows (wave w -> rows 16w..16w+15)
  const int r0 = tid >> 2;          // rows 0..63
  const int r1 = 64 + r0;           // rows 64..127
  const int cb = (tid & 3) * 8;     // element offset within row

  const size_t ebase = (size_t)e * S_TOK;
  const int tokA0 = (m0 + r0 < cnt) ? tok_list[ebase + m0 + r0] : 0;
  const int tokA1 = (m0 + r1 < cnt) ? tok_list[ebase + m0 + r1] : 0;
  const ushort_t* pA0 = A + (size_t)tokA0 * KDIM + cb;
  const ushort_t* pA1 = A + (size_t)tokA1 * KDIM + cb;
  const ushort_t* Be = B + (size_t)e * NDIM * KDIM;
  const ushort_t* pB0 = Be + (size_t)(n0 + r0) * KDIM + cb;
  const ushort_t* pB1 = Be + (size_t)(n0 + r1) * KDIM + cb;

  f32x4 acc[4][4];
#pragma unroll
  for (int i = 0; i < 4; ++i)
#pragma unroll
    for (int j = 0; j < 4; ++j)
      acc[i][j] = (f32x4){0.f, 0.f, 0.f, 0.f};

  constexpr int NK = KDIM / BK;

  // prologue: stage tile 0 into buf 0
  load_lds16(pA0, &As[0][w * 512]);
  load_lds16(pA1, &As[0][2048 + w * 512]);
  load_lds16(pB0, &Bs[0][w * 512]);
  load_lds16(pB1, &Bs[0][2048 + w * 512]);
  __syncthreads();

  int cur = 0;
  for (int t = 0; t < NK; ++t) {
    // issue next-tile loads into the other buffer (in flight during compute)
    if (t + 1 < NK) {
      const int k0 = (t + 1) * BK;
      const int nb = cur ^ 1;
      load_lds16(pA0 + k0, &As[nb][w * 512]);
      load_lds16(pA1 + k0, &As[nb][2048 + w * 512]);
      load_lds16(pB0 + k0, &Bs[nb][w * 512]);
      load_lds16(pB1 + k0, &Bs[nb][2048 + w * 512]);
    }

    const ushort_t* Ab = &As[cur][(wr + (lane & 15)) * BK + (lane >> 4) * 8];
    const ushort_t* Bb = &Bs[cur][(wc + (lane & 15)) * BK + (lane >> 4) * 8];
    bf16x8 a[4], b[4];
#pragma unroll
    for (int i = 0; i < 4; ++i) {
      a[i] = *(const bf16x8*)(Ab + i * 16 * BK);
      b[i] = *(const bf16x8*)(Bb + i * 16 * BK);
    }
#pragma unroll
    for (int mi = 0; mi < 4; ++mi)
#pragma unroll
      for (int ni = 0; ni < 4; ++ni)
        acc[mi][ni] = __builtin_amdgcn_mfma_f32_16x16x32_bf16(a[mi], b[ni], acc[mi][ni], 0, 0, 0);

    __syncthreads();   // drains vmcnt(0)+lgkmcnt(0): next buffer ready
    cur ^= 1;
  }

  const float* be = bias + (size_t)e * NDIM;
#pragma unroll
  for (int mi = 0; mi < 4; ++mi) {
#pragma unroll
    for (int r = 0; r < 4; ++r) {
      const int slot = m0 + wr + mi * 16 + ((lane >> 4) * 4) + r;
      if (slot >= cnt) continue;
      const int tok = tok_list[ebase + slot];
      if (EPI == 0) {
        ushort_t* hrow = Hout + (size_t)tok * NDIM;
#pragma unroll
        for (int ni = 0; ni < 4; ++ni) {
          const int col = n0 + wc + ni * 16 + (lane & 15);
          float v = acc[mi][ni][r] + be[col];
          v = 0.5f * v * (1.0f + erff(v * 0.70710678118654752f));
          hrow[col] = f32_bf16(v);
        }
      } else {
        const float p = prob[tok];
        float* orow = out + (size_t)tok * NDIM;
#pragma unroll
        for (int ni = 0; ni < 4; ++ni) {
          const int col = n0 + wc + ni * 16 + (lane & 15);
          orow[col] = (acc[mi][ni][r] + be[col]) * p;
        }
      }
    }
  }
}

extern "C" void kernel_launch(void* const* d_in, const int* in_sizes, int n_in,
                              void* d_out, int out_size, void* d_ws, size_t ws_size,
                              hipStream_t stream) {
  const float* x  = (const float*)d_in[0];
  const float* Wg = (const float*)d_in[1];
  const float* W1 = (const float*)d_in[2];
  const float* b1 = (const float*)d_in[3];
  const float* W2 = (const float*)d_in[4];
  const float* b2 = (const float*)d_in[5];
  float* out = (float*)d_out;

  const size_t MB = 1ull << 20;
  char* ws = (char*)d_ws;
  int* counts      = (int*)(ws);                 // 32 B
  int* plan        = (int*)(ws + 4096);          // ~1.1 KB
  float* prob      = (float*)(ws + 64 * 1024);   // 64 KB
  int* tok_list    = (int*)(ws + 128 * 1024);    // 512 KB
  ushort_t* xbf    = (ushort_t*)(ws + 1 * MB);   // 32 MB
  ushort_t* W1bf   = (ushort_t*)(ws + 33 * MB);  // 64 MB
  ushort_t* W2bf   = (ushort_t*)(ws + 97 * MB);  // 64 MB
  ushort_t* H      = (ushort_t*)(ws + 161 * MB); // 128 MB

  zero_counts_kernel<<<1, 64, 0, stream>>>(counts);
  gate_kernel<<<S_TOK / 4, 256, 0, stream>>>(x, Wg, xbf, prob, counts, tok_list);
  plan_kernel<<<1, 64, 0, stream>>>(counts, plan);

  cast_kernel<<<16384, 256, 0, stream>>>(W1, W1bf);
  cast_kernel<<<16384, 256, 0, stream>>>(W2, W2bf);

  ffn_kernel<D_DIM, F_DIM, 0><<<(F_DIM / BN) * NTILES_MAX, 256, 0, stream>>>(
      xbf, W1bf, b1, nullptr, counts, tok_list, plan, H, nullptr);

  ffn_kernel<F_DIM, D_DIM, 1><<<(D_DIM / BN) * NTILES_MAX, 256, 0, stream>>>(
      H, W2bf, b2, prob, counts, tok_list, plan, nullptr, out);
}